// Round 6
// baseline (349.408 us; speedup 1.0000x reference)
//
#include <hip/hip_runtime.h>

#define DEV __device__ __forceinline__

typedef __attribute__((ext_vector_type(4))) float f32x4;
typedef __attribute__((ext_vector_type(4))) unsigned short u16x4;
typedef __attribute__((ext_vector_type(8))) __bf16 bf16x8;

constexpr int NB = 16, SL = 2048, EM = 1024, DKD = 128;

DEV unsigned short f2bf(float f) {           // fp32 -> bf16 RNE
  unsigned int u = __float_as_uint(f);
  u += 0x7FFFu + ((u >> 16) & 1u);
  return (unsigned short)(u >> 16);
}

DEV f32x4 mfma16(bf16x8 a, bf16x8 b, f32x4 c) {
  return __builtin_amdgcn_mfma_f32_16x16x32_bf16(a, b, c, 0, 0, 0);
}

// async global->LDS DMA, 16B per lane; lds dst = wave-uniform base + lane*16
DEV void dma16(const void* g, void* l) {
  __builtin_amdgcn_global_load_lds(
      (const __attribute__((address_space(1))) unsigned int*)g,
      (__attribute__((address_space(3))) unsigned int*)l, 16, 0, 0);
}

DEV bf16x8 cvt8(f32x4 a, f32x4 b) {
  bf16x8 r;
  r[0] = (__bf16)a[0]; r[1] = (__bf16)a[1]; r[2] = (__bf16)a[2]; r[3] = (__bf16)a[3];
  r[4] = (__bf16)b[0]; r[5] = (__bf16)b[1]; r[6] = (__bf16)b[2]; r[7] = (__bf16)b[3];
  return r;
}

#define SBAR() __builtin_amdgcn_sched_barrier(0)

// ---------------------------------------------------------------------------
// prep_w: Wq/Wk/Wv fp32 [1024][128] -> bf16, tiled+swizzled. Block 0 also
// zeroes the mean-V accumulator mvg[NB][128].
// Chunk t = ((m*16 + kc)*128 + n)*8 + p holds W_m[k = kc*64 + (p^(n&7))*8 + e][n].
// ---------------------------------------------------------------------------
__global__ __launch_bounds__(256) void prep_w(
    const float* __restrict__ Wq, const float* __restrict__ Wk,
    const float* __restrict__ Wv, unsigned short* __restrict__ Wt,
    float* __restrict__ mvg)
{
  __shared__ unsigned short T[64 * 128];     // [kk][n] bf16
  const int tid = threadIdx.x;
  if (blockIdx.x == 0) {
    #pragma unroll
    for (int i = 0; i < NB * DKD / 256; ++i) mvg[i * 256 + tid] = 0.f;
  }
  const int m = blockIdx.x >> 4, kc = blockIdx.x & 15;   // 48 blocks
  const float* W = (m == 0) ? Wq : ((m == 1) ? Wk : Wv);
  #pragma unroll
  for (int it = 0; it < 8; ++it) {
    int idx = it * 256 + tid;                // 2048 f32x4 chunks
    int kk = idx >> 5, n4 = (idx & 31) * 4;
    f32x4 w4 = *(const f32x4*)(W + (size_t)(kc * 64 + kk) * DKD + n4);
    *(u16x4*)&T[kk * 128 + n4] =
        u16x4{ f2bf(w4[0]), f2bf(w4[1]), f2bf(w4[2]), f2bf(w4[3]) };
  }
  __syncthreads();
  #pragma unroll
  for (int it = 0; it < 4; ++it) {
    int idx = it * 256 + tid;                // 1024 out chunks, p fastest
    int p = idx & 7, n = idx >> 3;
    int c = p ^ (n & 7);
    unsigned short v[8];
    #pragma unroll
    for (int e = 0; e < 8; ++e) v[e] = T[(c * 8 + e) * 128 + n];
    size_t t = ((size_t)(m * 16 + kc) * 128 + n) * 8 + p;
    *(u16x4*)(Wt + t * 8)     = u16x4{v[0], v[1], v[2], v[3]};
    *(u16x4*)(Wt + t * 8 + 4) = u16x4{v[4], v[5], v[6], v[7]};
  }
}

// ---------------------------------------------------------------------------
// proj (merged): blockIdx&1 == 0 -> Q,K = ctx @ {Wq,Wk}; == 1 -> V = x @ Wv.
// 1024 blocks -> 2 live blocks/CU: the two paths' barrier/DMA stalls overlap.
// Dead blocks (rb >= len) return. A dbuf'd in LDS (full-iter DMA prefetch);
// B double-buffered in REGISTERS (bA/bB, loaded one iter ahead from the
// L2-resident pre-swizzled Wt). No manual vmcnt in the loop: the compiler's
// pre-MFMA wait on B(kc) counts younger [A-DMA(kc+2) x4 + B(kc+1) x8] and so
// also drains A(kc+1) before barrier2 -> A visibility across waves holds.
// ---------------------------------------------------------------------------
#define QK_STEP(KC, BCUR, BNXT)                                               \
  {                                                                           \
    SBAR();                                                                   \
    bf16x8 af[4][2];                                                          \
    _Pragma("unroll")                                                         \
    for (int rt = 0; rt < 4; ++rt) {                                          \
      const float* rbase = Als[(KC) & 1] + (rt * 16 + mm) * 64;               \
      _Pragma("unroll")                                                       \
      for (int ks = 0; ks < 2; ++ks) {                                        \
        f32x4 a0 = *(const f32x4*)(rbase + soff[ks][0]);                      \
        f32x4 a1 = *(const f32x4*)(rbase + soff[ks][1]);                      \
        af[rt][ks] = cvt8(a0, a1);                                            \
      }                                                                       \
    }                                                                         \
    __asm__ volatile("s_waitcnt lgkmcnt(0)" ::: "memory");                    \
    SBAR();                                                                   \
    __builtin_amdgcn_s_barrier();            /* safe to overwrite Als[kc&1] */\
    {                                                                         \
      const int kn = ((KC) + 2 < 16) ? ((KC) + 2) : 15;                       \
      _Pragma("unroll")                                                       \
      for (int i = 0; i < 4; ++i)                                             \
        dma16(asrc[i] + kn * 64,                                              \
              (char*)Als[(KC) & 1] + wave * 4096 + i * 1024);                 \
    }                                                                         \
    {                                                                         \
      const int kb1 = ((KC) + 1 < 16) ? ((KC) + 1) : 15;                      \
      _Pragma("unroll")                                                       \
      for (int lo = 0; lo < 4; ++lo)                                          \
        _Pragma("unroll")                                                     \
        for (int ks = 0; ks < 2; ++ks)                                        \
          BNXT[lo][ks] = *(const bf16x8*)(bbase[lo][ks] + (size_t)kb1 * 8192);\
    }                                                                         \
    _Pragma("unroll")                                                         \
    for (int lo = 0; lo < 4; ++lo)                                            \
      _Pragma("unroll")                                                       \
      for (int ks = 0; ks < 2; ++ks)                                          \
        _Pragma("unroll")                                                     \
        for (int rt = 0; rt < 4; ++rt)                                        \
          acc[rt][lo] = mfma16(af[rt][ks], BCUR[lo][ks], acc[rt][lo]);        \
    __builtin_amdgcn_s_barrier();            /* A(kc+1) visible everywhere */ \
  }

#define V_STEP(KC, BCUR, BNXT)                                                \
  {                                                                           \
    SBAR();                                                                   \
    bf16x8 af[4][2];                                                          \
    _Pragma("unroll")                                                         \
    for (int rt = 0; rt < 4; ++rt) {                                          \
      const float* rbase = Als[(KC) & 1] + (rt * 16 + mm) * 64;               \
      _Pragma("unroll")                                                       \
      for (int ks = 0; ks < 2; ++ks) {                                        \
        f32x4 a0 = *(const f32x4*)(rbase + soff[ks][0]);                      \
        f32x4 a1 = *(const f32x4*)(rbase + soff[ks][1]);                      \
        af[rt][ks] = cvt8(a0, a1);                                            \
      }                                                                       \
    }                                                                         \
    __asm__ volatile("s_waitcnt lgkmcnt(0)" ::: "memory");                    \
    SBAR();                                                                   \
    __builtin_amdgcn_s_barrier();                                             \
    {                                                                         \
      const int kn = ((KC) + 2 < 16) ? ((KC) + 2) : 15;                       \
      _Pragma("unroll")                                                       \
      for (int i = 0; i < 4; ++i)                                             \
        dma16(asrc[i] + kn * 64,                                              \
              (char*)Als[(KC) & 1] + wave * 4096 + i * 1024);                 \
    }                                                                         \
    {                                                                         \
      const int kb1 = ((KC) + 1 < 16) ? ((KC) + 1) : 15;                      \
      _Pragma("unroll")                                                       \
      for (int lo = 0; lo < 2; ++lo)                                          \
        _Pragma("unroll")                                                     \
        for (int ks = 0; ks < 2; ++ks)                                        \
          BNXT[lo][ks] = *(const bf16x8*)(bbase[lo][ks] + (size_t)kb1 * 8192);\
    }                                                                         \
    _Pragma("unroll")                                                         \
    for (int lo = 0; lo < 2; ++lo)                                            \
      _Pragma("unroll")                                                       \
      for (int ks = 0; ks < 2; ++ks)                                          \
        _Pragma("unroll")                                                     \
        for (int rt = 0; rt < 4; ++rt)                                        \
          acc[rt][lo] = mfma16(af[rt][ks], BCUR[lo][ks], acc[rt][lo]);        \
    __builtin_amdgcn_s_barrier();                                             \
  }

__global__ __launch_bounds__(256, 2) void proj(
    const float* __restrict__ ctx, const float* __restrict__ x,
    const unsigned short* __restrict__ Wt, const int* __restrict__ lens,
    unsigned short* __restrict__ Qo, unsigned short* __restrict__ Kz,
    unsigned short* __restrict__ Vz, float* __restrict__ mvg)
{
  __shared__ float Als[2][64 * 64];            // 32 KiB A dbuf
  const int tid = threadIdx.x;
  const int wave = tid >> 6, lane = tid & 63;
  const int quad = lane >> 4, mm = lane & 15;
  const int isv = blockIdx.x & 1;
  const int bi  = (int)blockIdx.x >> 1;        // 0..511 tile index
  const int rb  = bi * 64;
  const int bidx = bi >> 5;
  const int len = lens[bidx];
  if ((rb & (SL - 1)) >= len) return;          // dead block: outputs never read

  const float* Ain = isv ? x : ctx;

  // A-DMA source: instr i covers rows wave*16+i*4+(lane>>4); slot s=lane&15
  // sources chunk c=(s&8)|((s&7)^(row&7))  (involution, undone on read).
  const float* asrc[4];
  #pragma unroll
  for (int i = 0; i < 4; ++i) {
    const int rl_ = wave * 16 + i * 4 + (lane >> 4);
    const int cc  = (lane & 8) | ((lane & 7) ^ (rl_ & 7));
    asrc[i] = Ain + (size_t)(rb + rl_) * EM + cc * 4;
  }
  int soff[2][2];
  #pragma unroll
  for (int ks = 0; ks < 2; ++ks) {
    soff[ks][0] = (ks * 8 + ((quad * 2)     ^ (mm & 7))) * 4;
    soff[ks][1] = (ks * 8 + ((quad * 2 + 1) ^ (mm & 7))) * 4;
  }

  // ---- prologue: A(0)->Als[0], A(1)->Als[1]; wait A(0) (A(1) rides) ----
  #pragma unroll
  for (int i = 0; i < 4; ++i)
    dma16(asrc[i],      (char*)Als[0] + wave * 4096 + i * 1024);
  #pragma unroll
  for (int i = 0; i < 4; ++i)
    dma16(asrc[i] + 64, (char*)Als[1] + wave * 4096 + i * 1024);
  __asm__ volatile("s_waitcnt vmcnt(4)" ::: "memory");
  __builtin_amdgcn_s_barrier();

  if (!isv) {
    // ================= Q,K path =================
    f32x4 acc[4][4];
    #pragma unroll
    for (int i = 0; i < 4; ++i)
      #pragma unroll
      for (int j = 0; j < 4; ++j) acc[i][j] = f32x4{0.f, 0.f, 0.f, 0.f};

    const unsigned short* bbase[4][2];
    #pragma unroll
    for (int lo = 0; lo < 4; ++lo)
      #pragma unroll
      for (int ks = 0; ks < 2; ++ks) {
        const int nrow = (wave * 4 + lo) * 16 + mm;
        const int pp = (ks * 4 + quad) ^ (mm & 7);
        const int cs = nrow * 8 + pp;
        bbase[lo][ks] = Wt + ((size_t)(cs >> 10) * 16384 + (cs & 1023)) * 8;
      }
    bf16x8 bA[4][2], bB[4][2];
    #pragma unroll
    for (int lo = 0; lo < 4; ++lo)
      #pragma unroll
      for (int ks = 0; ks < 2; ++ks)
        bA[lo][ks] = *(const bf16x8*)(bbase[lo][ks]);   // B(0)

    #pragma unroll 1
    for (int t = 0; t < 8; ++t) {
      QK_STEP(2 * t,     bA, bB)
      QK_STEP(2 * t + 1, bB, bA)
    }
    __asm__ volatile("s_waitcnt vmcnt(0)" ::: "memory"); // drain clamped tail

    const float SCALE = 1.4426950408889634f * 0.08838834764831845f;
    #pragma unroll
    for (int rt = 0; rt < 4; ++rt)
      #pragma unroll
      for (int lo = 0; lo < 4; ++lo) {
        const int ctg = wave * 4 + lo;
        #pragma unroll
        for (int reg = 0; reg < 4; ++reg) {
          const int row = rb + rt * 16 + quad * 4 + reg;
          const int j = row & (SL - 1);
          const float val = acc[rt][lo][reg];
          if (ctg < 8) {
            const int d = ctg * 16 + mm;
            Qo[(size_t)row * DKD + d] = f2bf(val * ((j < len) ? SCALE : 0.f));
          } else {
            const int d = (ctg - 8) * 16 + mm;
            Kz[(size_t)row * DKD + (((d >> 3) ^ (j & 15)) * 8) + (d & 7)] = f2bf(val);
          }
        }
      }
  } else {
    // ================= V path =================
    f32x4 acc[4][2];
    #pragma unroll
    for (int i = 0; i < 4; ++i) {
      acc[i][0] = f32x4{0.f,0.f,0.f,0.f};
      acc[i][1] = f32x4{0.f,0.f,0.f,0.f};
    }
    const unsigned short* bbase[2][2];
    #pragma unroll
    for (int lo = 0; lo < 2; ++lo)
      #pragma unroll
      for (int ks = 0; ks < 2; ++ks) {
        const int nrow = (wave * 2 + lo) * 16 + mm;
        const int pp = (ks * 4 + quad) ^ (mm & 7);
        const int cs = nrow * 8 + pp;            // cs < 1024
        bbase[lo][ks] = Wt + ((size_t)2 * 16384 + cs) * 8;
      }
    bf16x8 bA[2][2], bB[2][2];
    #pragma unroll
    for (int lo = 0; lo < 2; ++lo)
      #pragma unroll
      for (int ks = 0; ks < 2; ++ks)
        bA[lo][ks] = *(const bf16x8*)(bbase[lo][ks]);   // B(0)

    #pragma unroll 1
    for (int t = 0; t < 8; ++t) {
      V_STEP(2 * t,     bA, bB)
      V_STEP(2 * t + 1, bB, bA)
    }
    __asm__ volatile("s_waitcnt vmcnt(0)" ::: "memory");

    #pragma unroll
    for (int rt = 0; rt < 4; ++rt)
      #pragma unroll
      for (int lo = 0; lo < 2; ++lo) {
        const int d = (wave * 2 + lo) * 16 + mm;
        const int row0 = rb + rt * 16 + quad * 4;
        const int b = row0 >> 11, j0 = row0 & (SL - 1);
        u16x4 pk = u16x4{ f2bf(acc[rt][lo][0]), f2bf(acc[rt][lo][1]),
                          f2bf(acc[rt][lo][2]), f2bf(acc[rt][lo][3]) };
        size_t off = (size_t)b * DKD * SL + (size_t)d * SL + (j0 & ~63)
                   + ((((j0 >> 3) & 7) ^ (d & 7)) * 8) + (j0 & 7);
        *(u16x4*)(Vz + off) = pk;
      }

    // mean-V accumulation: sum valid rows (j < len), f32, one atomic/(d)
    const int jb = rb & (SL - 1);
    #pragma unroll
    for (int lo = 0; lo < 2; ++lo) {
      const int d = (wave * 2 + lo) * 16 + mm;
      float part = 0.f;
      #pragma unroll
      for (int rt = 0; rt < 4; ++rt) {
        const int jr = jb + rt * 16 + quad * 4;
        #pragma unroll
        for (int reg = 0; reg < 4; ++reg)
          if (jr + reg < len) part += acc[rt][lo][reg];
      }
      part += __shfl_xor(part, 16);            // quad ^ 1
      part += __shfl_xor(part, 32);            // quad ^ 2
      if (quad == 0) atomicAdd(mvg + bidx * DKD + d, part);
    }
  }
}

// ---------------------------------------------------------------------------
// attn: flash attention, 64 q-rows/block, pipelined 64-key blocks (dbuf DMA).
// l accumulated as a 9th PV tile vs a ones-B fragment. Fully-padded query
// blocks broadcast mvg[b]/len. s_setprio(1) around MFMA clusters (T5).
// ---------------------------------------------------------------------------
__global__ __launch_bounds__(256, 2) void attn(
    const unsigned short* __restrict__ Qw, const unsigned short* __restrict__ Kz,
    const unsigned short* __restrict__ Vz, const float* __restrict__ mvg,
    const int* __restrict__ lens, float* __restrict__ out)
{
  __shared__ unsigned short Ks[2][64 * 128];   // [j][16 chunks x 8], swz c^(j&15)
  __shared__ unsigned short Vs[2][128 * 64];   // [d][8 chunks x 8],  swz c^(d&7)
  __shared__ unsigned short Ps[4][16 * 72];    // per-wave P [q][j+pad8]
  const int tid = threadIdx.x;
  const int wave = tid >> 6, lane = tid & 63;
  const int quad = lane >> 4, mm = lane & 15;
  const int b = blockIdx.y;
  const int qb = ((int)gridDim.x - 1 - (int)blockIdx.x) * 64;  // heavy blocks first
  const int len = lens[b];

  if (qb >= len) {
    // ---- mean path: every row = mvg[b]/len (precomputed by proj V path) ----
    const int dd = (tid & 31) * 4;
    const int r0 = tid >> 5;                 // 0..7
    const f32x4 m4 = *(const f32x4*)(mvg + b * DKD + dd);
    const float inv = 1.0f / (float)len;
    const f32x4 val = f32x4{ m4[0]*inv, m4[1]*inv, m4[2]*inv, m4[3]*inv };
    #pragma unroll
    for (int it = 0; it < 8; ++it) {
      const int row = qb + it * 8 + r0;
      *(f32x4*)(out + ((size_t)b * SL + row) * DKD + dd) = val;
    }
    return;
  }

  const int kend = min(qb + 64, len);
  const int nblk = (kend + 63) >> 6;
  const int irow0 = qb + wave * 16 + quad * 4;

  bf16x8 aQ[4];
  {
    const unsigned short* qbase =
        Qw + (size_t)(b * SL + qb + wave * 16 + mm) * DKD + quad * 8;
    #pragma unroll
    for (int cc = 0; cc < 4; ++cc) aQ[cc] = *(const bf16x8*)(qbase + cc * 32);
  }
  bf16x8 onesb;
  #pragma unroll
  for (int i = 0; i < 8; ++i) onesb[i] = (__bf16)1.0f;

  float mr[4];
  #pragma unroll
  for (int r = 0; r < 4; ++r) mr[r] = -__builtin_inff();
  f32x4 acc[8];
  #pragma unroll
  for (int i = 0; i < 8; ++i) acc[i] = f32x4{0.f,0.f,0.f,0.f};
  f32x4 accl = f32x4{0.f,0.f,0.f,0.f};       // l = P @ ones, rescaled with acc

  // prologue DMA: block 0 -> buf 0
  #pragma unroll
  for (int it = 0; it < 4; ++it) {
    int s = it * 256 + tid;
    dma16(Kz + (size_t)(b * SL) * DKD + (size_t)s * 8,
          (char*)Ks[0] + (it * 256 + wave * 64) * 16);
  }
  #pragma unroll
  for (int it = 0; it < 4; ++it) {
    int s = it * 256 + tid;
    int d = s >> 3, p = s & 7;
    dma16(Vz + (size_t)b * DKD * SL + (size_t)d * SL + p * 8,
          (char*)Vs[0] + (it * 256 + wave * 64) * 16);
  }

  #pragma unroll 1
  for (int blk = 0; blk < nblk; ++blk) {
    const int kb = blk * 64;
    __syncthreads();                       // drains DMA(blk)
    if (blk + 1 < nblk) {                  // issue next block's DMA
      const int kb1 = kb + 64;
      const int nb = (blk + 1) & 1;
      #pragma unroll
      for (int it = 0; it < 4; ++it) {
        int s = it * 256 + tid;
        dma16(Kz + (size_t)(b * SL + kb1) * DKD + (size_t)s * 8,
              (char*)Ks[nb] + (it * 256 + wave * 64) * 16);
      }
      #pragma unroll
      for (int it = 0; it < 4; ++it) {
        int s = it * 256 + tid;
        int d = s >> 3, p = s & 7;
        dma16(Vz + (size_t)b * DKD * SL + (size_t)d * SL + kb1 + p * 8,
              (char*)Vs[nb] + (it * 256 + wave * 64) * 16);
      }
    }
    const unsigned short* kbuf = Ks[blk & 1];
    const unsigned short* vbuf = Vs[blk & 1];

    // S = Q K^T : 4 key-tiles
    f32x4 s4[4];
    __builtin_amdgcn_s_setprio(1);
    #pragma unroll
    for (int nt = 0; nt < 4; ++nt) {
      f32x4 c = f32x4{0.f,0.f,0.f,0.f};
      const int j = nt * 16 + mm;
      #pragma unroll
      for (int cc = 0; cc < 4; ++cc) {
        const int pp = (cc * 4 + quad) ^ mm;
        bf16x8 kf = *(const bf16x8*)(kbuf + j * 128 + pp * 8);
        c = mfma16(aQ[cc], kf, c);
      }
      s4[nt] = c;
    }
    __builtin_amdgcn_s_setprio(0);

    float alpha[4];
    #pragma unroll
    for (int reg = 0; reg < 4; ++reg) {
      const int jl = min(irow0 + reg + 1, len);
      float v0 = (kb + mm      < jl) ? s4[0][reg] : -__builtin_inff();
      float v1 = (kb + 16 + mm < jl) ? s4[1][reg] : -__builtin_inff();
      float v2 = (kb + 32 + mm < jl) ? s4[2][reg] : -__builtin_inff();
      float v3 = (kb + 48 + mm < jl) ? s4[3][reg] : -__builtin_inff();
      float mx = fmaxf(fmaxf(v0, v1), fmaxf(v2, v3));
      #pragma unroll
      for (int xm = 1; xm < 16; xm <<= 1) mx = fmaxf(mx, __shfl_xor(mx, xm));
      const float mn = fmaxf(mr[reg], mx);
      alpha[reg] = __builtin_amdgcn_exp2f(mr[reg] - mn);
      const float p0 = __builtin_amdgcn_exp2f(v0 - mn);
      const float p1 = __builtin_amdgcn_exp2f(v1 - mn);
      const float p2 = __builtin_amdgcn_exp2f(v2 - mn);
      const float p3 = __builtin_amdgcn_exp2f(v3 - mn);
      mr[reg] = mn;
      const int prow = quad * 4 + reg;
      Ps[wave][prow * 72 + mm]      = f2bf(p0);
      Ps[wave][prow * 72 + 16 + mm] = f2bf(p1);
      Ps[wave][prow * 72 + 32 + mm] = f2bf(p2);
      Ps[wave][prow * 72 + 48 + mm] = f2bf(p3);
    }
    #pragma unroll
    for (int nt = 0; nt < 8; ++nt) {
      f32x4 a = acc[nt];
      a[0] *= alpha[0]; a[1] *= alpha[1]; a[2] *= alpha[2]; a[3] *= alpha[3];
      acc[nt] = a;
    }
    accl[0] *= alpha[0]; accl[1] *= alpha[1];
    accl[2] *= alpha[2]; accl[3] *= alpha[3];
    __asm__ volatile("s_waitcnt lgkmcnt(0)" ::: "memory");  // P writes -> reads
    bf16x8 aP[2];
    #pragma unroll
    for (int ks = 0; ks < 2; ++ks)
      aP[ks] = *(const bf16x8*)(&Ps[wave][mm * 72 + ks * 32 + quad * 8]);
    __builtin_amdgcn_s_setprio(1);
    #pragma unroll
    for (int ks = 0; ks < 2; ++ks) {
      #pragma unroll
      for (int nt = 0; nt < 8; ++nt) {
        const int pp = (ks * 4 + quad) ^ (mm & 7);
        bf16x8 vf = *(const bf16x8*)(vbuf + (nt * 16 + mm) * 64 + pp * 8);
        acc[nt] = mfma16(aP[ks], vf, acc[nt]);
      }
      accl = mfma16(aP[ks], onesb, accl);    // row-sum tile (all cols equal)
    }
    __builtin_amdgcn_s_setprio(0);
  }

  #pragma unroll
  for (int reg = 0; reg < 4; ++reg) {
    const float rl = 1.0f / accl[reg];
    const size_t base = ((size_t)b * SL + irow0 + reg) * DKD + mm;
    #pragma unroll
    for (int nt = 0; nt < 8; ++nt)
      out[base + nt * 16] = acc[nt][reg] * rl;
  }
}

// ---------------------------------------------------------------------------
extern "C" void kernel_launch(void* const* d_in, const int* in_sizes, int n_in,
                              void* d_out, int out_size, void* d_ws, size_t ws_size,
                              hipStream_t stream) {
  const float* x    = (const float*)d_in[0];
  const float* ctx  = (const float*)d_in[1];
  const int*   lens = (const int*)d_in[2];
  const float* Wq   = (const float*)d_in[3];
  const float* Wk   = (const float*)d_in[4];
  const float* Wv   = (const float*)d_in[5];
  float* out = (float*)d_out;

  const size_t QKV = (size_t)NB * SL * DKD * sizeof(unsigned short); // 8 MiB each
  const size_t WTSZ = (size_t)3 * 16 * 128 * 8 * 8 * sizeof(unsigned short); // 768 KiB
  const size_t MVSZ = (size_t)NB * DKD * sizeof(float);              // 8 KiB
  if (ws_size < 3 * QKV + WTSZ + MVSZ) return;
  unsigned short* Qws = (unsigned short*)d_ws;
  unsigned short* Kzs = (unsigned short*)((char*)d_ws + QKV);
  unsigned short* Vzs = (unsigned short*)((char*)d_ws + 2 * QKV);
  unsigned short* Wt  = (unsigned short*)((char*)d_ws + 3 * QKV);
  float*          mvg = (float*)((char*)d_ws + 3 * QKV + WTSZ);

  prep_w<<<dim3(48), 256, 0, stream>>>(Wq, Wk, Wv, Wt, mvg);
  proj  <<<dim3(2 * NB * SL / 64), 256, 0, stream>>>(ctx, x, Wt, lens,
                                                     Qws, Kzs, Vzs, mvg);
  attn  <<<dim3(SL / 64, NB), 256, 0, stream>>>(Qws, Kzs, Vzs, mvg, lens, out);
}